// Round 5
// baseline (148.760 us; speedup 1.0000x reference)
//
#include <hip/hip_runtime.h>

// R5: 256-thread WG per row (4096 WGs -> 8 resident/CU = 32 waves/CU full
// occupancy, 16 queued/CU backfills L-imbalance). Keeps R3/R4 algebra:
//   pooled_emb = (sum_r count[r]*emb[r])/(k*L)  (histogram trick),
//   binary-vocab counts = register index sums (no atomics),
//   pool commutes with the 32x32 second layers (no relu between).
// New: token loads pre-issued to registers before first barrier; all
// embedding/matmul loops have compile-time trip counts (half-wave if/else)
// so loads pipeline instead of forming serial load->fma chains; in-wave
// shuffles replace two barriers (5 __syncthreads total).

#define BDIM 256

__global__ __launch_bounds__(BDIM, 8)
void mlpreg_kernel(const float* __restrict__ cont_p,
                   const float* __restrict__ cont_c,
                   const int* __restrict__ cat_p,
                   const int* __restrict__ cat_c,
                   const int* __restrict__ lengths,
                   const float* __restrict__ w_p1, const float* __restrict__ b_p1,
                   const float* __restrict__ w_p2, const float* __restrict__ b_p2,
                   const float* __restrict__ w_c1, const float* __restrict__ b_c1,
                   const float* __restrict__ w_c2, const float* __restrict__ b_c2,
                   const float* __restrict__ emb_g,  const float* __restrict__ emb_k,
                   const float* __restrict__ emb_pr, const float* __restrict__ emb_j,
                   const float* __restrict__ emb_r,  const float* __restrict__ emb_pl,
                   const float* __restrict__ emb_a,
                   const float* __restrict__ w_fc1, const float* __restrict__ b_fc1,
                   const float* __restrict__ w_fc2, const float* __restrict__ b_fc2,
                   float* __restrict__ out)
{
    constexpr int S = 256;
    __shared__ float sContP[S * 3];   // 3072 B
    __shared__ float sContC[S * 2];   // 2048 B
    __shared__ int   hist[96];        // job@0(11) rep@11(34) place@45(19) add@64(31)
    __shared__ int   sBin[4][3];      // per-wave binary-column sums
    __shared__ float sRedP[128], sRedC[128];
    __shared__ float sPacc[64];
    __shared__ float sPooled[128];
    __shared__ float sRedF[BDIM];

    const int tid = threadIdx.x;
    const int b   = blockIdx.x;
    int L = lengths[b];
    if (L < 1) L = 1;
    if (L > S) L = S;
    const float invL = 1.0f / (float)L;
    const float Lf   = (float)L;

    const int*   kp = cat_p  + (size_t)b * (S * 5);
    const int*   kc = cat_c  + (size_t)b * (S * 2);
    const float* gp = cont_p + (size_t)b * (S * 3);
    const float* gc = cont_c + (size_t)b * (S * 2);

    // ---- pre-issue all token-data loads into registers (before any barrier)
    const int n3 = 3 * L, n2 = 2 * L, n5 = 5 * L;
    float rp0 = (tid       < n3) ? gp[tid]       : 0.f;
    float rp1 = (tid + 256 < n3) ? gp[tid + 256] : 0.f;
    float rp2 = (tid + 512 < n3) ? gp[tid + 512] : 0.f;
    float rc0 = (tid       < n2) ? gc[tid]       : 0.f;
    float rc1 = (tid + 256 < n2) ? gc[tid + 256] : 0.f;
    int rk[5];
    #pragma unroll
    for (int j = 0; j < 5; ++j) {
        int ii = tid + 256 * j;
        rk[j] = (ii < n5) ? kp[ii] : -1;
    }
    int rq0 = (tid       < n2) ? kc[tid]       : -1;
    int rq1 = (tid + 256 < n2) ? kc[tid + 256] : -1;

    if (tid < 96) hist[tid] = 0;
    __syncthreads();

    // ---- LDS staging + histogram (atomics) + binary register sums ----
    if (tid       < n3) sContP[tid]       = rp0;
    if (tid + 256 < n3) sContP[tid + 256] = rp1;
    if (tid + 512 < n3) sContP[tid + 512] = rp2;
    if (tid       < n2) sContC[tid]       = rc0;
    if (tid + 256 < n2) sContC[tid + 256] = rc1;

    int sg = 0, sk = 0, spr = 0;
    #pragma unroll
    for (int j = 0; j < 5; ++j) {
        int ii = tid + 256 * j;
        if (ii < n5) {
            int col = ii % 5, v = rk[j];
            if      (col == 0) sg  += v;
            else if (col == 1) sk  += v;
            else if (col == 2) spr += v;
            else if (col == 3) atomicAdd(&hist[v], 1);       // job(11)
            else               atomicAdd(&hist[11 + v], 1);  // rep(34)
        }
    }
    // cat_c flat parity: even index -> place, odd -> add (256 is even)
    if (rq0 >= 0) atomicAdd(&hist[((tid & 1) ? 64 : 45) + rq0], 1);
    if (rq1 >= 0) atomicAdd(&hist[((tid & 1) ? 64 : 45) + rq1], 1);

    #pragma unroll
    for (int d = 32; d; d >>= 1) {
        sg  += __shfl_xor(sg,  d);
        sk  += __shfl_xor(sk,  d);
        spr += __shfl_xor(spr, d);
    }
    const int wv = tid >> 6, lane = tid & 63;
    if (lane == 0) { sBin[wv][0] = sg; sBin[wv][1] = sk; sBin[wv][2] = spr; }
    __syncthreads();

    // ---- token relu-MLP loop: 8 half-wave groups over token strides ----
    const int g8 = tid >> 5, ch = tid & 31, h = lane >> 5;
    const float wp0 = w_p1[ch], wp1 = w_p1[32 + ch], wp2 = w_p1[64 + ch], bp = b_p1[ch];
    const float wc0 = w_c1[ch], wc1 = w_c1[32 + ch], bc = b_c1[ch];
    float accP = 0.f, accC = 0.f;
    #pragma unroll 2
    for (int t = g8; t < L; t += 8) {
        float c0 = sContP[3 * t], c1 = sContP[3 * t + 1], c2 = sContP[3 * t + 2];
        float d0 = sContC[2 * t], d1 = sContC[2 * t + 1];
        accP += fmaxf(fmaf(c0, wp0, fmaf(c1, wp1, fmaf(c2, wp2, bp))), 0.f);
        accC += fmaxf(fmaf(d0, wc0, fmaf(d1, wc1, bc)), 0.f);
    }
    accP += __shfl_down(accP, 32);
    accC += __shfl_down(accC, 32);
    if (lane < 32) { sRedP[wv * 32 + ch] = accP; sRedC[wv * 32 + ch] = accC; }
    __syncthreads();

    // ---- P3: wave0 = ep, wave1 = ec (constant-trip halves, pipelined loads);
    //          wave2/3 = pooled-relu reductions ----
    if (wv == 0) {
        float sgT  = (float)(sBin[0][0] + sBin[1][0] + sBin[2][0] + sBin[3][0]);
        float skT  = (float)(sBin[0][1] + sBin[1][1] + sBin[2][1] + sBin[3][1]);
        float sprT = (float)(sBin[0][2] + sBin[1][2] + sBin[2][2] + sBin[3][2]);
        float s = 0.f;
        if (h == 0) {
            s  = fmaf(Lf - sgT,  emb_g[ch],  sgT  * emb_g[32 + ch]);
            s += fmaf(Lf - sprT, emb_pr[ch], sprT * emb_pr[32 + ch]);
            #pragma unroll
            for (int r = 0; r < 6; ++r)  s = fmaf((float)hist[r],      emb_j[r * 32 + ch], s);
            #pragma unroll
            for (int r = 0; r < 17; ++r) s = fmaf((float)hist[11 + r], emb_r[r * 32 + ch], s);
        } else {
            s = fmaf(Lf - skT, emb_k[ch], skT * emb_k[32 + ch]);
            #pragma unroll
            for (int r = 6; r < 11; ++r)  s = fmaf((float)hist[r],      emb_j[r * 32 + ch], s);
            #pragma unroll
            for (int r = 17; r < 34; ++r) s = fmaf((float)hist[11 + r], emb_r[r * 32 + ch], s);
        }
        s += __shfl_down(s, 32);
        if (h == 0) sPooled[ch] = s * (invL * 0.2f);
    } else if (wv == 1) {
        float s = 0.f;
        if (h == 0) {
            #pragma unroll
            for (int r = 0; r < 10; ++r) s = fmaf((float)hist[45 + r], emb_pl[r * 32 + ch], s);
            #pragma unroll
            for (int r = 0; r < 16; ++r) s = fmaf((float)hist[64 + r], emb_a[r * 32 + ch], s);
        } else {
            #pragma unroll
            for (int r = 10; r < 19; ++r) s = fmaf((float)hist[45 + r], emb_pl[r * 32 + ch], s);
            #pragma unroll
            for (int r = 16; r < 31; ++r) s = fmaf((float)hist[64 + r], emb_a[r * 32 + ch], s);
        }
        s += __shfl_down(s, 32);
        if (h == 0) sPooled[32 + ch] = s * (invL * 0.5f);
    } else if (wv == 2) {
        if (lane < 32)
            sPacc[ch] = (sRedP[ch] + sRedP[32 + ch] + sRedP[64 + ch] + sRedP[96 + ch]) * invL;
    } else {
        if (lane < 32)
            sPacc[32 + ch] = (sRedC[ch] + sRedC[32 + ch] + sRedC[64 + ch] + sRedC[96 + ch]) * invL;
    }
    __syncthreads();

    // ---- P4: 32x32 second layers on waves 2/3, k split across halves ----
    if (wv == 2) {
        const int kb = h * 16;
        float v = (h == 0) ? b_p2[ch] : 0.f;
        #pragma unroll
        for (int k = 0; k < 16; ++k) v = fmaf(sPacc[kb + k], w_p2[(kb + k) * 32 + ch], v);
        v += __shfl_down(v, 32);
        if (h == 0) sPooled[64 + ch] = v;
    } else if (wv == 3) {
        const int kb = h * 16;
        float v = (h == 0) ? b_c2[ch] : 0.f;
        #pragma unroll
        for (int k = 0; k < 16; ++k) v = fmaf(sPacc[32 + kb + k], w_c2[(kb + k) * 32 + ch], v);
        v += __shfl_down(v, 32);
        if (h == 0) sPooled[96 + ch] = v;
    }
    __syncthreads();

    // ---- P5: fc1 128->64 over all 256 threads (quarter-k per lane) ----
    {
        const int o = tid & 63, part = tid >> 6;
        const float* wk = w_fc1 + (size_t)(part * 32) * 64 + o;
        const float* xk = sPooled + part * 32;
        float v0 = 0.f, v1 = 0.f, v2 = 0.f, v3 = 0.f;
        #pragma unroll
        for (int k = 0; k < 32; k += 4) {
            v0 = fmaf(xk[k + 0], wk[(size_t)(k + 0) * 64], v0);
            v1 = fmaf(xk[k + 1], wk[(size_t)(k + 1) * 64], v1);
            v2 = fmaf(xk[k + 2], wk[(size_t)(k + 2) * 64], v2);
            v3 = fmaf(xk[k + 3], wk[(size_t)(k + 3) * 64], v3);
        }
        sRedF[tid] = (v0 + v1) + (v2 + v3);
    }
    __syncthreads();

    // ---- P6: wave 0 combines fc1, does fc2 butterfly, stores ----
    if (wv == 0) {
        float hv = b_fc1[lane] + (sRedF[lane] + sRedF[64 + lane])
                               + (sRedF[128 + lane] + sRedF[192 + lane]);
        hv = fmaxf(hv, 0.f);
        float p0 = hv * w_fc2[lane * 2 + 0];
        float p1 = hv * w_fc2[lane * 2 + 1];
        #pragma unroll
        for (int d = 32; d; d >>= 1) {
            p0 += __shfl_xor(p0, d);
            p1 += __shfl_xor(p1, d);
        }
        if (lane == 0) {
            float2 o2;
            o2.x = fmaxf(p0 + b_fc2[0], 0.f);
            o2.y = fmaxf(p1 + b_fc2[1], 0.f);
            *(float2*)&out[(size_t)b * 2] = o2;
        }
    }
}

extern "C" void kernel_launch(void* const* d_in, const int* in_sizes, int n_in,
                              void* d_out, int out_size, void* d_ws, size_t ws_size,
                              hipStream_t stream) {
    const float* cont_p = (const float*)d_in[0];
    const float* cont_c = (const float*)d_in[1];
    const int*   cat_p  = (const int*)d_in[2];
    const int*   cat_c  = (const int*)d_in[3];
    const int*   lens   = (const int*)d_in[4];
    const float* w_p1   = (const float*)d_in[5];
    const float* b_p1   = (const float*)d_in[6];
    const float* w_p2   = (const float*)d_in[7];
    const float* b_p2   = (const float*)d_in[8];
    const float* w_c1   = (const float*)d_in[9];
    const float* b_c1   = (const float*)d_in[10];
    const float* w_c2   = (const float*)d_in[11];
    const float* b_c2   = (const float*)d_in[12];
    const float* emb_g  = (const float*)d_in[13];
    const float* emb_k  = (const float*)d_in[14];
    const float* emb_pr = (const float*)d_in[15];
    const float* emb_j  = (const float*)d_in[16];
    const float* emb_r  = (const float*)d_in[17];
    const float* emb_pl = (const float*)d_in[18];
    const float* emb_a  = (const float*)d_in[19];
    const float* w_fc1  = (const float*)d_in[20];
    const float* b_fc1  = (const float*)d_in[21];
    const float* w_fc2  = (const float*)d_in[22];
    const float* b_fc2  = (const float*)d_in[23];
    float* out = (float*)d_out;

    const int B = 4096;
    hipLaunchKernelGGL(mlpreg_kernel, dim3(B), dim3(BDIM), 0, stream,
                       cont_p, cont_c, cat_p, cat_c, lens,
                       w_p1, b_p1, w_p2, b_p2, w_c1, b_c1, w_c2, b_c2,
                       emb_g, emb_k, emb_pr, emb_j, emb_r, emb_pl, emb_a,
                       w_fc1, b_fc1, w_fc2, b_fc2, out);
}